// Round 1
// baseline (1287.272 us; speedup 1.0000x reference)
//
#include <hip/hip_runtime.h>
#include <cstdint>
#include <cstddef>
#include <cmath>

// ---------------- problem constants ----------------
constexpr int Bb = 2, Ll = 4096, D8c = 256, CFc = 128, HWc = 65536, WWc = 25;
constexpr int BLc = Bb * Ll;        // 8192
constexpr int NCRc = 2 * BLc;       // 16384 rows of local_desc / center

// ---------------- output layout (floats) ----------------
constexpr size_t OUT_CM  = (size_t)NCRc * WWc * CFc;          // 52,428,800
constexpr size_t OUT_JID = OUT_CM + (size_t)Bb * Ll * Ll;     // +33,554,432
constexpr size_t OUT_VAL = OUT_JID + (size_t)BLc;

// ---------------- workspace layout (float offsets) ----------------
constexpr size_t W_R0   = 0;                                   // 33,554,432: sim, then f/h (in place)
constexpr size_t W_CENT = 33554432;                            // 16384*128
constexpr size_t W_PM   = W_CENT + (size_t)NCRc * CFc;         // 256*128
constexpr size_t W_CV   = W_PM + 256 * 128;                    // 128
constexpr size_t W_PE   = W_CV + 128;                          // 25*128
constexpr size_t W_RMAX = W_PE + WWc * CFc;                    // 8192
constexpr size_t W_RSUM = W_RMAX + BLc;                        // 8192
constexpr size_t W_CMAX = W_RSUM + BLc;                        // 8192
constexpr size_t W_CSUM = W_CMAX + BLc;                        // 8192
constexpr size_t W_PCM  = W_CSUM + BLc;                        // 16*8192 (f32 partial col max)
constexpr size_t W_PCS  = W_PCM + (size_t)16 * BLc;            // 16*8192 DOUBLES (partial col sum)
constexpr size_t W_RCMV = W_PCS + (size_t)32 * BLc;            // 8192 (row cm max val)
constexpr size_t W_RCMA = W_RCMV + BLc;                        // 8192 (int: row cm argmax)
constexpr size_t W_PCCM = W_RCMA + BLc;                        // 16*8192 (partial col max of cm)
constexpr size_t W_JINT = W_PCCM + (size_t)16 * BLc;           // 8192 (int j_ids)

// ---------------- prep: pm = proj_w@mw2, cvec = proj_b@mw2+merge_b, pos-embed ----------------
__global__ void prep_kernel(const float* __restrict__ proj_w, const float* __restrict__ proj_b,
                            const float* __restrict__ merge_w, const float* __restrict__ merge_b,
                            float* __restrict__ ws) {
  const int blk = blockIdx.x;
  const int d = threadIdx.x;  // 128 threads
  if (blk < 256) {
    float acc = 0.f;
    for (int k = 0; k < 128; ++k)
      acc = fmaf(proj_w[blk * 128 + k], merge_w[(128 + k) * 128 + d], acc);
    ws[W_PM + blk * 128 + d] = acc;
  } else if (blk == 256) {
    float acc = merge_b[d];
    for (int k = 0; k < 128; ++k)
      acc = fmaf(proj_b[k], merge_w[(128 + k) * 128 + d], acc);
    ws[W_CV + d] = acc;
  } else {
    const float c = -0.07195578415606394f;  // -ln(10000)/128
    const int p = d >> 1;
    const float divp = expf((float)(2 * p) * c);
    for (int m = 0; m < WWc; ++m) {
      float ang = (float)m * divp;
      ws[W_PE + m * 128 + d] = (d & 1) ? cosf(ang) : sinf(ang);
    }
  }
}

// ---------------- sim GEMM: sim[b,i,j] = dot(feat0[b,i,:],feat1[b,j,:]) * 10/65536 ----------------
__global__ __launch_bounds__(256) void sim_gemm(const float* __restrict__ fa,
                                                const float* __restrict__ fb,
                                                float* __restrict__ sim) {
  const int bb = blockIdx.z;
  const int i0 = blockIdx.y * 128, j0 = blockIdx.x * 128;
  const float* A  = fa + (size_t)bb * Ll * D8c;
  const float* Bm = fb + (size_t)bb * Ll * D8c;
  __shared__ float As[16][132], Bs[16][132];
  const int t = threadIdx.x, ty = t >> 4, tx = t & 15;
  const int lr = t >> 2, lk = (t & 3) << 2;
  float acc[8][8] = {};
  for (int k0 = 0; k0 < D8c; k0 += 16) {
    float4 a0 = *(const float4*)(A + (size_t)(i0 + lr) * D8c + k0 + lk);
    float4 a1 = *(const float4*)(A + (size_t)(i0 + lr + 64) * D8c + k0 + lk);
    float4 b0 = *(const float4*)(Bm + (size_t)(j0 + lr) * D8c + k0 + lk);
    float4 b1 = *(const float4*)(Bm + (size_t)(j0 + lr + 64) * D8c + k0 + lk);
    __syncthreads();
    As[lk + 0][lr] = a0.x; As[lk + 1][lr] = a0.y; As[lk + 2][lr] = a0.z; As[lk + 3][lr] = a0.w;
    As[lk + 0][lr + 64] = a1.x; As[lk + 1][lr + 64] = a1.y; As[lk + 2][lr + 64] = a1.z; As[lk + 3][lr + 64] = a1.w;
    Bs[lk + 0][lr] = b0.x; Bs[lk + 1][lr] = b0.y; Bs[lk + 2][lr] = b0.z; Bs[lk + 3][lr] = b0.w;
    Bs[lk + 0][lr + 64] = b1.x; Bs[lk + 1][lr + 64] = b1.y; Bs[lk + 2][lr + 64] = b1.z; Bs[lk + 3][lr + 64] = b1.w;
    __syncthreads();
#pragma unroll
    for (int k = 0; k < 16; ++k) {
      float a[8], b[8];
      *(float4*)&a[0] = *(const float4*)&As[k][ty * 8];
      *(float4*)&a[4] = *(const float4*)&As[k][ty * 8 + 4];
      *(float4*)&b[0] = *(const float4*)&Bs[k][tx * 8];
      *(float4*)&b[4] = *(const float4*)&Bs[k][tx * 8 + 4];
#pragma unroll
      for (int ii = 0; ii < 8; ++ii)
#pragma unroll
        for (int jj = 0; jj < 8; ++jj)
          acc[ii][jj] = fmaf(a[ii], b[jj], acc[ii][jj]);
    }
  }
  const float scale = 10.0f / 65536.0f;  // (1/d)*(1/d)/0.1 ; /256 is exact, so order-safe
  float* C = sim + ((size_t)bb * Ll + i0 + ty * 8) * Ll + j0 + tx * 8;
#pragma unroll
  for (int ii = 0; ii < 8; ++ii) {
    float4 o0, o1;
    o0.x = acc[ii][0] * scale; o0.y = acc[ii][1] * scale; o0.z = acc[ii][2] * scale; o0.w = acc[ii][3] * scale;
    o1.x = acc[ii][4] * scale; o1.y = acc[ii][5] * scale; o1.z = acc[ii][6] * scale; o1.w = acc[ii][7] * scale;
    *(float4*)(C + (size_t)ii * Ll) = o0;
    *(float4*)(C + (size_t)ii * Ll + 4) = o1;
  }
}

// ---------------- row softmax stats (axis=2): max + f64 sum ----------------
__global__ __launch_bounds__(256) void row_stats(const float* __restrict__ sim, float* __restrict__ ws) {
  const int ri = blockIdx.x;
  const float* s = sim + (size_t)ri * Ll;
  const int t = threadIdx.x;
  float xs[16];
  float m = -INFINITY;
#pragma unroll
  for (int it = 0; it < 16; ++it) {
    xs[it] = s[it * 256 + t];
    m = fmaxf(m, xs[it]);
  }
  __shared__ float sm[256];
  sm[t] = m; __syncthreads();
  for (int o = 128; o; o >>= 1) { if (t < o) sm[t] = fmaxf(sm[t], sm[t + o]); __syncthreads(); }
  const float M = sm[0];
  double su = 0.0;
#pragma unroll
  for (int it = 0; it < 16; ++it) su += (double)expf(xs[it] - M);
  __shared__ double sd[256];
  sd[t] = su; __syncthreads();
  for (int o = 128; o; o >>= 1) { if (t < o) sd[t] += sd[t + o]; __syncthreads(); }
  if (t == 0) { ws[W_RMAX + ri] = M; ws[W_RSUM + ri] = (float)sd[0]; }
}

// ---------------- col softmax stats (axis=1): segmented two-pass ----------------
__global__ __launch_bounds__(256) void col_stats(const float* __restrict__ sim, float* __restrict__ ws) {
  const int bx = blockIdx.x;       // 0..31 : b*16 + column-group
  const int seg = blockIdx.y;      // 0..15 : row segment of 256
  const int b = bx >> 4, jb = (bx & 15) << 8;
  const int t = threadIdx.x;
  const int j = jb + t;
  const float* s = sim + ((size_t)b * Ll + seg * 256) * Ll + j;
  float m = -INFINITY;
  for (int r = 0; r < 256; ++r) m = fmaxf(m, s[(size_t)r * Ll]);
  double su = 0.0;
  for (int r = 0; r < 256; ++r) su += (double)expf(s[(size_t)r * Ll] - m);
  const int cg = b * Ll + j;
  ws[W_PCM + seg * BLc + cg] = m;
  ((double*)(ws + W_PCS))[seg * BLc + cg] = su;
}

__global__ void col_merge(float* __restrict__ ws) {
  const int cg = blockIdx.x * 256 + threadIdx.x;  // grid 32
  float M = -INFINITY;
  for (int sg = 0; sg < 16; ++sg) M = fmaxf(M, ws[W_PCM + sg * BLc + cg]);
  double S = 0.0;
  for (int sg = 0; sg < 16; ++sg) {
    double ps = ((const double*)(ws + W_PCS))[sg * BLc + cg];
    S += ps * exp((double)(ws[W_PCM + sg * BLc + cg] - M));
  }
  ws[W_CMAX + cg] = M;
  ws[W_CSUM + cg] = (float)S;
}

// ---------------- cm = softmax_col * softmax_row ; per-row max+argmax ----------------
__global__ __launch_bounds__(256) void cm_kernel(float* __restrict__ ws, float* __restrict__ out) {
  const int ri = blockIdx.x;
  const int b = ri >> 12;
  const int t = threadIdx.x;
  const float* s = ws + W_R0 + (size_t)ri * Ll;
  const float rm = ws[W_RMAX + ri];
  const float rsum = ws[W_RSUM + ri];
  const float* cmax = ws + W_CMAX + (size_t)b * Ll;
  const float* csum = ws + W_CSUM + (size_t)b * Ll;
  float* crow = out + OUT_CM + (size_t)ri * Ll;
  float bv = -1.f; int bj = 0;
  for (int it = 0; it < 16; ++it) {
    const int j = it * 256 + t;  // ascending per thread -> first-tie kept
    const float x = s[j];
    const float p1 = expf(x - cmax[j]) / csum[j];
    const float p2 = expf(x - rm) / rsum;
    const float v = p1 * p2;
    crow[j] = v;
    if (v > bv) { bv = v; bj = j; }
  }
  __shared__ float sv[256]; __shared__ int sj[256];
  sv[t] = bv; sj[t] = bj; __syncthreads();
  for (int o = 128; o; o >>= 1) {
    if (t < o) {
      if (sv[t + o] > sv[t] || (sv[t + o] == sv[t] && sj[t + o] < sj[t])) {
        sv[t] = sv[t + o]; sj[t] = sj[t + o];
      }
    }
    __syncthreads();
  }
  if (!t) { ws[W_RCMV + ri] = sv[0]; ((int*)ws)[W_RCMA + ri] = sj[0]; }
}

// ---------------- column max of cm (for mutual-NN) ----------------
__global__ __launch_bounds__(256) void colcm_stats(const float* __restrict__ out, float* __restrict__ ws) {
  const int bx = blockIdx.x, seg = blockIdx.y;
  const int b = bx >> 4, jb = (bx & 15) << 8;
  const int t = threadIdx.x, j = jb + t;
  const float* c = out + OUT_CM + ((size_t)b * Ll + seg * 256) * Ll + j;
  float M = -1.f;
  for (int r = 0; r < 256; ++r) M = fmaxf(M, c[(size_t)r * Ll]);
  ws[W_PCCM + seg * BLc + b * Ll + j] = M;
}

// ---------------- mutual-NN: j_ids, valid ----------------
__global__ void finalize_kernel(float* __restrict__ ws, float* __restrict__ out) {
  const int ri = blockIdx.x * 256 + threadIdx.x;  // grid 32
  const int b = ri >> 12;
  const int jv = ((const int*)ws)[W_RCMA + ri];
  float cmx = -1.f;
  for (int s = 0; s < 16; ++s) cmx = fmaxf(cmx, ws[W_PCCM + s * BLc + b * Ll + jv]);
  const float rv = ws[W_RCMV + ri];
  const bool mut = (rv == cmx);   // bitwise: both fmax-chains over identical stored values
  const int jid = mut ? jv : 0;
  ((int*)ws)[W_JINT + ri] = jid;
  out[OUT_JID + ri] = (float)jid;
  out[OUT_VAL + ri] = mut ? 1.f : 0.f;
}

// ---------------- 1x1 conv + BN + mish -> f [map*2+b][pix][128] (pixel-major) ----------------
__global__ __launch_bounds__(256) void convbn_kernel(
    const float* __restrict__ x0, const float* __restrict__ x1,
    const float* __restrict__ w, const float* __restrict__ cb,
    const float* __restrict__ gamma, const float* __restrict__ beta,
    const float* __restrict__ mean, const float* __restrict__ var,
    float* __restrict__ ws) {
  const int mb = blockIdx.y;  // map*2+b
  const float* x = (mb >= 2 ? x1 : x0) + (size_t)(mb & 1) * D8c * HWc;
  const int p0 = blockIdx.x * 128;
  float* F = ws + W_R0 + ((size_t)mb * HWc) * 128;
  __shared__ float As[16][128];   // [k][pixel] (natural: source is channel-major)
  __shared__ float Wsm[16][128];  // [k][d]
  const int t = threadIdx.x, ty = t >> 4, tx = t & 15;
  const int lc = t >> 4, lp = (t & 15) << 3;
  float acc[8][8] = {};
  for (int k0 = 0; k0 < D8c; k0 += 16) {
    float4 a0 = *(const float4*)(x + (size_t)(k0 + lc) * HWc + p0 + lp);
    float4 a1 = *(const float4*)(x + (size_t)(k0 + lc) * HWc + p0 + lp + 4);
    float4 w0 = *(const float4*)(w + (size_t)(k0 + lc) * 128 + lp);
    float4 w1 = *(const float4*)(w + (size_t)(k0 + lc) * 128 + lp + 4);
    __syncthreads();
    *(float4*)&As[lc][lp] = a0;  *(float4*)&As[lc][lp + 4] = a1;
    *(float4*)&Wsm[lc][lp] = w0; *(float4*)&Wsm[lc][lp + 4] = w1;
    __syncthreads();
#pragma unroll
    for (int k = 0; k < 16; ++k) {
      float a[8], b[8];
      *(float4*)&a[0] = *(const float4*)&As[k][ty * 8];
      *(float4*)&a[4] = *(const float4*)&As[k][ty * 8 + 4];
      *(float4*)&b[0] = *(const float4*)&Wsm[k][tx * 8];
      *(float4*)&b[4] = *(const float4*)&Wsm[k][tx * 8 + 4];
#pragma unroll
      for (int ii = 0; ii < 8; ++ii)
#pragma unroll
        for (int jj = 0; jj < 8; ++jj)
          acc[ii][jj] = fmaf(a[ii], b[jj], acc[ii][jj]);
    }
  }
#pragma unroll
  for (int jj = 0; jj < 8; ++jj) {
    const int dd = tx * 8 + jj;
    const float g = gamma[dd] / sqrtf(var[dd] + 1e-5f);
    const float bias = (cb[dd] - mean[dd]) * g + beta[dd];
#pragma unroll
    for (int ii = 0; ii < 8; ++ii) {
      const float v = acc[ii][jj] * g + bias;
      const float e = expf(v);
      const float u = 1.f + e, u2 = u * u;
      acc[ii][jj] = (v > 20.f) ? v : v * (u2 - 1.f) / (u2 + 1.f);  // x*tanh(softplus(x))
    }
  }
#pragma unroll
  for (int ii = 0; ii < 8; ++ii) {
    float4 o0 = {acc[ii][0], acc[ii][1], acc[ii][2], acc[ii][3]};
    float4 o1 = {acc[ii][4], acc[ii][5], acc[ii][6], acc[ii][7]};
    float* dst = F + (size_t)(p0 + ty * 8 + ii) * 128 + tx * 8;
    *(float4*)dst = o0; *(float4*)(dst + 4) = o1;
  }
}

// ---------------- h = f @ mw1 (in place, row-wise) ----------------
__global__ __launch_bounds__(256) void hgemm(float* __restrict__ ws, const float* __restrict__ merge_w) {
  float* F = ws + W_R0;
  const int m0 = blockIdx.x * 128;
  __shared__ float As[16][132];  // transposed: [k][row]
  __shared__ float Wsm[16][128];
  const int t = threadIdx.x, ty = t >> 4, tx = t & 15;
  const int lr = t >> 2, lk = (t & 3) << 2;
  const int wc = t >> 4, wd = (t & 15) << 3;
  float acc[8][8] = {};
  for (int k0 = 0; k0 < 128; k0 += 16) {
    float4 a0 = *(const float4*)(F + (size_t)(m0 + lr) * 128 + k0 + lk);
    float4 a1 = *(const float4*)(F + (size_t)(m0 + lr + 64) * 128 + k0 + lk);
    float4 w0 = *(const float4*)(merge_w + (size_t)(k0 + wc) * 128 + wd);
    float4 w1 = *(const float4*)(merge_w + (size_t)(k0 + wc) * 128 + wd + 4);
    __syncthreads();
    As[lk + 0][lr] = a0.x; As[lk + 1][lr] = a0.y; As[lk + 2][lr] = a0.z; As[lk + 3][lr] = a0.w;
    As[lk + 0][lr + 64] = a1.x; As[lk + 1][lr + 64] = a1.y; As[lk + 2][lr + 64] = a1.z; As[lk + 3][lr + 64] = a1.w;
    *(float4*)&Wsm[wc][wd] = w0; *(float4*)&Wsm[wc][wd + 4] = w1;
    __syncthreads();
#pragma unroll
    for (int k = 0; k < 16; ++k) {
      float a[8], b[8];
      *(float4*)&a[0] = *(const float4*)&As[k][ty * 8];
      *(float4*)&a[4] = *(const float4*)&As[k][ty * 8 + 4];
      *(float4*)&b[0] = *(const float4*)&Wsm[k][tx * 8];
      *(float4*)&b[4] = *(const float4*)&Wsm[k][tx * 8 + 4];
#pragma unroll
      for (int ii = 0; ii < 8; ++ii)
#pragma unroll
        for (int jj = 0; jj < 8; ++jj)
          acc[ii][jj] = fmaf(a[ii], b[jj], acc[ii][jj]);
    }
  }
#pragma unroll
  for (int ii = 0; ii < 8; ++ii) {
    float4 o0 = {acc[ii][0], acc[ii][1], acc[ii][2], acc[ii][3]};
    float4 o1 = {acc[ii][4], acc[ii][5], acc[ii][6], acc[ii][7]};
    float* dst = F + (size_t)(m0 + ty * 8 + ii) * 128 + tx * 8;
    *(float4*)dst = o0; *(float4*)(dst + 4) = o1;
  }
}

// ---------------- centc = gathered_feat @ pm + cvec ----------------
__global__ __launch_bounds__(256) void center_gemm(const float* __restrict__ f0,
                                                   const float* __restrict__ f1,
                                                   float* __restrict__ ws) {
  const int n0 = blockIdx.x * 128;
  const int t = threadIdx.x;
  __shared__ int rsrc[128];
  if (t < 128) {
    const int n = n0 + t;
    int r;
    if (n < BLc) r = n;
    else {
      const int m2 = n - BLc;
      const int b = m2 >> 12, l = m2 & 4095;
      r = BLc + b * Ll + ((const int*)ws)[W_JINT + b * Ll + l];
    }
    rsrc[t] = r;
  }
  __syncthreads();
  __shared__ float As[16][132];
  __shared__ float Wsm[16][128];
  const int ty = t >> 4, tx = t & 15;
  const int lr = t >> 2, lk = (t & 3) << 2;
  const int wc = t >> 4, wd = (t & 15) << 3;
  const float* pm = ws + W_PM;
  float acc[8][8] = {};
  for (int k0 = 0; k0 < 256; k0 += 16) {
    const int r0 = rsrc[lr], r1 = rsrc[lr + 64];
    const float* p0 = (r0 < BLc) ? (f0 + (size_t)r0 * 256) : (f1 + (size_t)(r0 - BLc) * 256);
    const float* p1 = (r1 < BLc) ? (f0 + (size_t)r1 * 256) : (f1 + (size_t)(r1 - BLc) * 256);
    float4 a0 = *(const float4*)(p0 + k0 + lk);
    float4 a1 = *(const float4*)(p1 + k0 + lk);
    float4 w0 = *(const float4*)(pm + (size_t)(k0 + wc) * 128 + wd);
    float4 w1 = *(const float4*)(pm + (size_t)(k0 + wc) * 128 + wd + 4);
    __syncthreads();
    As[lk + 0][lr] = a0.x; As[lk + 1][lr] = a0.y; As[lk + 2][lr] = a0.z; As[lk + 3][lr] = a0.w;
    As[lk + 0][lr + 64] = a1.x; As[lk + 1][lr + 64] = a1.y; As[lk + 2][lr + 64] = a1.z; As[lk + 3][lr + 64] = a1.w;
    *(float4*)&Wsm[wc][wd] = w0; *(float4*)&Wsm[wc][wd + 4] = w1;
    __syncthreads();
#pragma unroll
    for (int k = 0; k < 16; ++k) {
      float a[8], b[8];
      *(float4*)&a[0] = *(const float4*)&As[k][ty * 8];
      *(float4*)&a[4] = *(const float4*)&As[k][ty * 8 + 4];
      *(float4*)&b[0] = *(const float4*)&Wsm[k][tx * 8];
      *(float4*)&b[4] = *(const float4*)&Wsm[k][tx * 8 + 4];
#pragma unroll
      for (int ii = 0; ii < 8; ++ii)
#pragma unroll
        for (int jj = 0; jj < 8; ++jj)
          acc[ii][jj] = fmaf(a[ii], b[jj], acc[ii][jj]);
    }
  }
  const float* cv = ws + W_CV;
#pragma unroll
  for (int ii = 0; ii < 8; ++ii)
#pragma unroll
    for (int jj = 0; jj < 8; ++jj)
      ws[W_CENT + (size_t)(n0 + ty * 8 + ii) * 128 + tx * 8 + jj] = acc[ii][jj] + cv[tx * 8 + jj];
}

// ---------------- local_desc = gather(h) + centc + pe ----------------
__global__ __launch_bounds__(256) void gather_out(const float* __restrict__ ws, float* __restrict__ out) {
  const int n = blockIdx.x;
  const int t = threadIdx.x;
  const int d = t & 127, th = t >> 7;
  int b, l, mapsel;
  if (n < BLc) { mapsel = 0; b = n >> 12; l = n & 4095; }
  else {
    mapsel = 1;
    const int m2 = n - BLc;
    b = m2 >> 12;
    l = ((const int*)ws)[W_JINT + b * Ll + (m2 & 4095)];
  }
  const float* hb = ws + W_R0 + ((size_t)(mapsel * 2 + b) * HWc) * 128;
  const int y0 = ((l >> 6) << 2) - 2, x0 = ((l & 63) << 2) - 2;
  const float cvn = ws[W_CENT + (size_t)n * 128 + d];
  float* ob = out + (size_t)n * WWc * 128 + d;
  const float* pe = ws + W_PE;
  for (int m = th; m < WWc; m += 2) {
    const int dy = m / 5, dx = m - dy * 5;
    const int y = y0 + dy, x = x0 + dx;
    float hv = 0.f;
    if ((unsigned)y < 256u && (unsigned)x < 256u)
      hv = hb[((size_t)(y << 8) + x) * 128 + d];
    ob[(size_t)m * 128] = hv + cvn + pe[m * 128 + d];
  }
}

// ---------------- launcher ----------------
extern "C" void kernel_launch(void* const* d_in, const int* in_sizes, int n_in,
                              void* d_out, int out_size, void* d_ws, size_t ws_size,
                              hipStream_t stream) {
  (void)in_sizes; (void)n_in; (void)out_size; (void)ws_size;
  const float* f0  = (const float*)d_in[0];
  const float* f1  = (const float*)d_in[1];
  const float* fm0 = (const float*)d_in[2];
  const float* fm1 = (const float*)d_in[3];
  const float* cw  = (const float*)d_in[4];
  const float* cb  = (const float*)d_in[5];
  const float* bg  = (const float*)d_in[6];
  const float* bbt = (const float*)d_in[7];
  const float* bm  = (const float*)d_in[8];
  const float* bv  = (const float*)d_in[9];
  const float* pw  = (const float*)d_in[10];
  const float* pb  = (const float*)d_in[11];
  const float* mw  = (const float*)d_in[12];
  const float* mbb = (const float*)d_in[13];
  float* out = (float*)d_out;
  float* ws  = (float*)d_ws;

  prep_kernel<<<258, 128, 0, stream>>>(pw, pb, mw, mbb, ws);
  sim_gemm<<<dim3(32, 32, 2), 256, 0, stream>>>(f0, f1, ws + W_R0);
  row_stats<<<BLc, 256, 0, stream>>>(ws + W_R0, ws);
  col_stats<<<dim3(32, 16), 256, 0, stream>>>(ws + W_R0, ws);
  col_merge<<<32, 256, 0, stream>>>(ws);
  cm_kernel<<<BLc, 256, 0, stream>>>(ws, out);
  colcm_stats<<<dim3(32, 16), 256, 0, stream>>>(out, ws);
  finalize_kernel<<<32, 256, 0, stream>>>(ws, out);
  // fine-feature path (reuses sim region of ws after cm phase is done)
  convbn_kernel<<<dim3(512, 4), 256, 0, stream>>>(fm0, fm1, cw, cb, bg, bbt, bm, bv, ws);
  hgemm<<<2048, 256, 0, stream>>>(ws, mw);
  center_gemm<<<128, 256, 0, stream>>>(f0, f1, ws);
  gather_out<<<NCRc, 256, 0, stream>>>(ws, out);
}

// Round 2
// 1135.792 us; speedup vs baseline: 1.1334x; 1.1334x over previous
//
#include <hip/hip_runtime.h>
#include <cstdint>
#include <cstddef>
#include <cmath>

// ---------------- problem constants ----------------
constexpr int Bb = 2, Ll = 4096, D8c = 256, CFc = 128, HWc = 65536, WWc = 25;
constexpr int BLc = Bb * Ll;        // 8192
constexpr int NCRc = 2 * BLc;       // 16384 rows of local_desc / center

// ---------------- output layout (floats) ----------------
constexpr size_t OUT_CM  = (size_t)NCRc * WWc * CFc;          // 52,428,800
constexpr size_t OUT_JID = OUT_CM + (size_t)Bb * Ll * Ll;     // +33,554,432
constexpr size_t OUT_VAL = OUT_JID + (size_t)BLc;

// ---------------- workspace layout (float offsets) ----------------
constexpr size_t W_R0   = 0;                                   // 33,554,432: sim, then h (in place)
constexpr size_t W_CENT = 33554432;                            // 16384*128
constexpr size_t W_PM   = W_CENT + (size_t)NCRc * CFc;         // 256*128
constexpr size_t W_CV   = W_PM + 256 * 128;                    // 128
constexpr size_t W_PE   = W_CV + 128;                          // 25*128
constexpr size_t W_RMAX = W_PE + WWc * CFc;                    // 8192
constexpr size_t W_RSUM = W_RMAX + BLc;                        // 8192
constexpr size_t W_CMAX = W_RSUM + BLc;                        // 8192
constexpr size_t W_CSUM = W_CMAX + BLc;                        // 8192
constexpr size_t W_PCM  = W_CSUM + BLc;                        // 16*8192 (f32 partial col max)
constexpr size_t W_PCS  = W_PCM + (size_t)16 * BLc;            // 16*8192 DOUBLES (partial col sum)
constexpr size_t W_RCMV = W_PCS + (size_t)32 * BLc;            // 8192 (row cm max val)
constexpr size_t W_RCMA = W_RCMV + BLc;                        // 8192 (int: row cm argmax)
constexpr size_t W_PCCM = W_RCMA + BLc;                        // 16*8192 (partial col max of cm)
constexpr size_t W_JINT = W_PCCM + (size_t)16 * BLc;           // 8192 (int j_ids)
// transient regions inside W_CENT (dead before center_gemm writes W_CENT):
constexpr size_t W_WT   = W_CENT;                              // 32768 floats = 128 KB (4 slices x 2 planes x 16KB)
constexpr size_t W_MWT  = W_CENT + 32768;                      // 16384 floats = 64 KB (2 planes x 32KB)
constexpr size_t W_G    = W_CENT + 32768 + 16384;              // 128
constexpr size_t W_BB   = W_G + 128;                           // 128

typedef __attribute__((ext_vector_type(8))) short short8;
typedef __attribute__((ext_vector_type(4))) float f32x4;
typedef __attribute__((ext_vector_type(2))) unsigned int uint2v;
typedef __attribute__((ext_vector_type(4))) unsigned int uint4v;

__device__ inline unsigned short rneb(float v) {            // f32 -> bf16 RNE
  unsigned u = __builtin_bit_cast(unsigned, v);
  u += 0x7fffu + ((u >> 16) & 1u);
  return (unsigned short)(u >> 16);
}
__device__ inline float bf2f(unsigned short h) {
  return __builtin_bit_cast(float, (unsigned)h << 16);
}
__device__ inline void gload_lds16(const void* g, void* l) {
  __builtin_amdgcn_global_load_lds((const __attribute__((address_space(1))) unsigned int*)g,
                                   (__attribute__((address_space(3))) unsigned int*)l, 16, 0, 0);
}
#define TRREAD(dst, a) asm volatile("ds_read_b64_tr_b16 %0, %1" : "=v"(dst) : "v"(a))

// ---------------- prep: pm = proj_w@mw2, cvec = proj_b@mw2+merge_b, pos-embed ----------------
__global__ void prep_kernel(const float* __restrict__ proj_w, const float* __restrict__ proj_b,
                            const float* __restrict__ merge_w, const float* __restrict__ merge_b,
                            float* __restrict__ ws) {
  const int blk = blockIdx.x;
  const int d = threadIdx.x;  // 128 threads
  if (blk < 256) {
    float acc = 0.f;
    for (int k = 0; k < 128; ++k)
      acc = fmaf(proj_w[blk * 128 + k], merge_w[(128 + k) * 128 + d], acc);
    ws[W_PM + blk * 128 + d] = acc;
  } else if (blk == 256) {
    float acc = merge_b[d];
    for (int k = 0; k < 128; ++k)
      acc = fmaf(proj_b[k], merge_w[(128 + k) * 128 + d], acc);
    ws[W_CV + d] = acc;
  } else {
    const float c = -0.07195578415606394f;  // -ln(10000)/128
    const int p = d >> 1;
    const float divp = expf((float)(2 * p) * c);
    for (int m = 0; m < WWc; ++m) {
      float ang = (float)m * divp;
      ws[W_PE + m * 128 + d] = (d & 1) ? cosf(ang) : sinf(ang);
    }
  }
}

// ---------------- prep2: split/transpose weights for MFMA path ----------------
// wsWT  : 4 slices x 2 planes x [128cf][64k] bf16, XOR-swizzled 16B slots (slot ^= cf&7)
// wsMWT : 2 planes x [128co][128ci] bf16 (mwT[co][ci] = merge_w[ci][co], rows 0..127)
// W_G/W_BB: folded BN scale/bias per cf
__global__ void prep2_kernel(const float* __restrict__ w, const float* __restrict__ mw,
                             const float* __restrict__ cb, const float* __restrict__ gamma,
                             const float* __restrict__ beta, const float* __restrict__ mean,
                             const float* __restrict__ var, float* __restrict__ ws) {
  const int blk = blockIdx.x, t = threadIdx.x;  // 128 threads
  char* wt = (char*)(ws + W_WT);
  char* mwt = (char*)(ws + W_MWT);
  if (blk < 256) {
    const float v = w[blk * 128 + t];            // w[k_glob][cf=t]
    const unsigned short h = rneb(v);
    const unsigned short l = rneb(v - bf2f(h));
    const int s = blk >> 6, kloc = blk & 63;
    const size_t off = (size_t)t * 128 + (size_t)((((kloc >> 3) ^ (t & 7)) << 4)) + (size_t)(kloc & 7) * 2;
    *(unsigned short*)(wt + (size_t)(s * 2 + 0) * 16384 + off) = h;
    *(unsigned short*)(wt + (size_t)(s * 2 + 1) * 16384 + off) = l;
  } else if (blk < 384) {
    const int co = blk - 256, ci = t;
    const float v = mw[ci * 128 + co];           // merge_w rows 0..127
    const unsigned short h = rneb(v);
    const unsigned short l = rneb(v - bf2f(h));
    *(unsigned short*)(mwt + (size_t)co * 256 + ci * 2) = h;
    *(unsigned short*)(mwt + 32768 + (size_t)co * 256 + ci * 2) = l;
  } else {
    const float g = gamma[t] * rsqrtf(var[t] + 1e-5f);
    ws[W_G + t] = g;
    ws[W_BB + t] = (cb[t] - mean[t]) * g + beta[t];
  }
}

// ---------------- sim GEMM (f32 vector, unchanged) ----------------
__global__ __launch_bounds__(256) void sim_gemm(const float* __restrict__ fa,
                                                const float* __restrict__ fb,
                                                float* __restrict__ sim) {
  const int bb = blockIdx.z;
  const int i0 = blockIdx.y * 128, j0 = blockIdx.x * 128;
  const float* A  = fa + (size_t)bb * Ll * D8c;
  const float* Bm = fb + (size_t)bb * Ll * D8c;
  __shared__ float As[16][132], Bs[16][132];
  const int t = threadIdx.x, ty = t >> 4, tx = t & 15;
  const int lr = t >> 2, lk = (t & 3) << 2;
  float acc[8][8] = {};
  for (int k0 = 0; k0 < D8c; k0 += 16) {
    float4 a0 = *(const float4*)(A + (size_t)(i0 + lr) * D8c + k0 + lk);
    float4 a1 = *(const float4*)(A + (size_t)(i0 + lr + 64) * D8c + k0 + lk);
    float4 b0 = *(const float4*)(Bm + (size_t)(j0 + lr) * D8c + k0 + lk);
    float4 b1 = *(const float4*)(Bm + (size_t)(j0 + lr + 64) * D8c + k0 + lk);
    __syncthreads();
    As[lk + 0][lr] = a0.x; As[lk + 1][lr] = a0.y; As[lk + 2][lr] = a0.z; As[lk + 3][lr] = a0.w;
    As[lk + 0][lr + 64] = a1.x; As[lk + 1][lr + 64] = a1.y; As[lk + 2][lr + 64] = a1.z; As[lk + 3][lr + 64] = a1.w;
    Bs[lk + 0][lr] = b0.x; Bs[lk + 1][lr] = b0.y; Bs[lk + 2][lr] = b0.z; Bs[lk + 3][lr] = b0.w;
    Bs[lk + 0][lr + 64] = b1.x; Bs[lk + 1][lr + 64] = b1.y; Bs[lk + 2][lr + 64] = b1.z; Bs[lk + 3][lr + 64] = b1.w;
    __syncthreads();
#pragma unroll
    for (int k = 0; k < 16; ++k) {
      float a[8], b[8];
      *(float4*)&a[0] = *(const float4*)&As[k][ty * 8];
      *(float4*)&a[4] = *(const float4*)&As[k][ty * 8 + 4];
      *(float4*)&b[0] = *(const float4*)&Bs[k][tx * 8];
      *(float4*)&b[4] = *(const float4*)&Bs[k][tx * 8 + 4];
#pragma unroll
      for (int ii = 0; ii < 8; ++ii)
#pragma unroll
        for (int jj = 0; jj < 8; ++jj)
          acc[ii][jj] = fmaf(a[ii], b[jj], acc[ii][jj]);
    }
  }
  const float scale = 10.0f / 65536.0f;
  float* C = sim + ((size_t)bb * Ll + i0 + ty * 8) * Ll + j0 + tx * 8;
#pragma unroll
  for (int ii = 0; ii < 8; ++ii) {
    float4 o0, o1;
    o0.x = acc[ii][0] * scale; o0.y = acc[ii][1] * scale; o0.z = acc[ii][2] * scale; o0.w = acc[ii][3] * scale;
    o1.x = acc[ii][4] * scale; o1.y = acc[ii][5] * scale; o1.z = acc[ii][6] * scale; o1.w = acc[ii][7] * scale;
    *(float4*)(C + (size_t)ii * Ll) = o0;
    *(float4*)(C + (size_t)ii * Ll + 4) = o1;
  }
}

// ---------------- row softmax stats ----------------
__global__ __launch_bounds__(256) void row_stats(const float* __restrict__ sim, float* __restrict__ ws) {
  const int ri = blockIdx.x;
  const float* s = sim + (size_t)ri * Ll;
  const int t = threadIdx.x;
  float xs[16];
  float m = -INFINITY;
#pragma unroll
  for (int it = 0; it < 16; ++it) {
    xs[it] = s[it * 256 + t];
    m = fmaxf(m, xs[it]);
  }
  __shared__ float sm[256];
  sm[t] = m; __syncthreads();
  for (int o = 128; o; o >>= 1) { if (t < o) sm[t] = fmaxf(sm[t], sm[t + o]); __syncthreads(); }
  const float M = sm[0];
  double su = 0.0;
#pragma unroll
  for (int it = 0; it < 16; ++it) su += (double)expf(xs[it] - M);
  __shared__ double sd[256];
  sd[t] = su; __syncthreads();
  for (int o = 128; o; o >>= 1) { if (t < o) sd[t] += sd[t + o]; __syncthreads(); }
  if (t == 0) { ws[W_RMAX + ri] = M; ws[W_RSUM + ri] = (float)sd[0]; }
}

// ---------------- col softmax stats ----------------
__global__ __launch_bounds__(256) void col_stats(const float* __restrict__ sim, float* __restrict__ ws) {
  const int bx = blockIdx.x;
  const int seg = blockIdx.y;
  const int b = bx >> 4, jb = (bx & 15) << 8;
  const int t = threadIdx.x;
  const int j = jb + t;
  const float* s = sim + ((size_t)b * Ll + seg * 256) * Ll + j;
  float m = -INFINITY;
  for (int r = 0; r < 256; ++r) m = fmaxf(m, s[(size_t)r * Ll]);
  double su = 0.0;
  for (int r = 0; r < 256; ++r) su += (double)expf(s[(size_t)r * Ll] - m);
  const int cg = b * Ll + j;
  ws[W_PCM + seg * BLc + cg] = m;
  ((double*)(ws + W_PCS))[seg * BLc + cg] = su;
}

__global__ void col_merge(float* __restrict__ ws) {
  const int cg = blockIdx.x * 256 + threadIdx.x;
  float M = -INFINITY;
  for (int sg = 0; sg < 16; ++sg) M = fmaxf(M, ws[W_PCM + sg * BLc + cg]);
  double S = 0.0;
  for (int sg = 0; sg < 16; ++sg) {
    double ps = ((const double*)(ws + W_PCS))[sg * BLc + cg];
    S += ps * exp((double)(ws[W_PCM + sg * BLc + cg] - M));
  }
  ws[W_CMAX + cg] = M;
  ws[W_CSUM + cg] = (float)S;
}

// ---------------- cm + per-row max/argmax ----------------
__global__ __launch_bounds__(256) void cm_kernel(float* __restrict__ ws, float* __restrict__ out) {
  const int ri = blockIdx.x;
  const int b = ri >> 12;
  const int t = threadIdx.x;
  const float* s = ws + W_R0 + (size_t)ri * Ll;
  const float rm = ws[W_RMAX + ri];
  const float rsum = ws[W_RSUM + ri];
  const float* cmax = ws + W_CMAX + (size_t)b * Ll;
  const float* csum = ws + W_CSUM + (size_t)b * Ll;
  float* crow = out + OUT_CM + (size_t)ri * Ll;
  float bv = -1.f; int bj = 0;
  for (int it = 0; it < 16; ++it) {
    const int j = it * 256 + t;
    const float x = s[j];
    const float p1 = expf(x - cmax[j]) / csum[j];
    const float p2 = expf(x - rm) / rsum;
    const float v = p1 * p2;
    crow[j] = v;
    if (v > bv) { bv = v; bj = j; }
  }
  __shared__ float sv[256]; __shared__ int sj[256];
  sv[t] = bv; sj[t] = bj; __syncthreads();
  for (int o = 128; o; o >>= 1) {
    if (t < o) {
      if (sv[t + o] > sv[t] || (sv[t + o] == sv[t] && sj[t + o] < sj[t])) {
        sv[t] = sv[t + o]; sj[t] = sj[t + o];
      }
    }
    __syncthreads();
  }
  if (!t) { ws[W_RCMV + ri] = sv[0]; ((int*)ws)[W_RCMA + ri] = sj[0]; }
}

// ---------------- column max of cm ----------------
__global__ __launch_bounds__(256) void colcm_stats(const float* __restrict__ out, float* __restrict__ ws) {
  const int bx = blockIdx.x, seg = blockIdx.y;
  const int b = bx >> 4, jb = (bx & 15) << 8;
  const int t = threadIdx.x, j = jb + t;
  const float* c = out + OUT_CM + ((size_t)b * Ll + seg * 256) * Ll + j;
  float M = -1.f;
  for (int r = 0; r < 256; ++r) M = fmaxf(M, c[(size_t)r * Ll]);
  ws[W_PCCM + seg * BLc + b * Ll + j] = M;
}

// ---------------- mutual-NN ----------------
__global__ void finalize_kernel(float* __restrict__ ws, float* __restrict__ out) {
  const int ri = blockIdx.x * 256 + threadIdx.x;
  const int b = ri >> 12;
  const int jv = ((const int*)ws)[W_RCMA + ri];
  float cmx = -1.f;
  for (int s = 0; s < 16; ++s) cmx = fmaxf(cmx, ws[W_PCCM + s * BLc + b * Ll + jv]);
  const float rv = ws[W_RCMV + ri];
  const bool mut = (rv == cmx);
  const int jid = mut ? jv : 0;
  ((int*)ws)[W_JINT + ri] = jid;
  out[OUT_JID + ri] = (float)jid;
  out[OUT_VAL + ri] = mut ? 1.f : 0.f;
}

// ---------------- FUSED: convbn(mish) + hgemm, split-2 bf16 MFMA ----------------
// Per block: 128 pixels x 128 cf. Phase1: f = mish(bn(w^T . x)) via D1[cf][p] = wT . x
// (x B-operand k-runs via ds_read_b64_tr_b16 from subtiled LDS). Phase2: h = f @ mw1.
__global__ __launch_bounds__(256, 2) void fused_conv_kernel(
    const float* __restrict__ x0, const float* __restrict__ x1, float* __restrict__ ws) {
  __shared__ __align__(16) char lds[65536];
  const int mb = blockIdx.y;
  const float* x = (mb >= 2 ? x1 : x0) + (size_t)(mb & 1) * D8c * HWc;
  const int p0 = blockIdx.x * 128;
  const int t = threadIdx.x;
  const int wv = t >> 6, l = t & 63;
  const int ln = l & 15, g = l >> 4, l7 = l & 7;
  const int wr = wv >> 1, wc = wv & 1;
  const char* wt = (const char*)(ws + W_WT);
  const char* mwt = (const char*)(ws + W_MWT);
  const unsigned ldsb = (unsigned)(size_t)(&lds[0]);

  // folded BN constants for this lane's 16 cf values
  float gval[4][4], bval[4][4];
#pragma unroll
  for (int m = 0; m < 4; ++m)
#pragma unroll
    for (int r = 0; r < 4; ++r) {
      const int cf = wr * 64 + m * 16 + g * 4 + r;
      gval[m][r] = ws[W_G + cf];
      bval[m][r] = ws[W_BB + cf];
    }

  f32x4 acc[4][4] = {};

  // staging mapping: thread handles k = t&63 (slice-local), 32 pixels pq*32..+31
  const int sk = t & 63, pq = t >> 6;
  const int skk = sk >> 5, sjh = (sk >> 2) & 1, sg = (sk >> 3) & 3, skr = sk & 3;

  float4 xv[8];
  {
    const float* xr = x + (size_t)sk * HWc + p0 + pq * 32;
#pragma unroll
    for (int i = 0; i < 8; ++i) xv[i] = *(const float4*)(xr + i * 4);
  }

  for (int s = 0; s < 4; ++s) {
    __syncthreads();
    // stage W slice s (pre-swizzled in ws): planes -> lds[32768] (hi), lds[49152] (lo)
    {
      const char* src = wt + (size_t)(s * 2) * 16384;
#pragma unroll
      for (int r = 0; r < 4; ++r)
        gload_lds16(src + r * 4096 + t * 16, lds + 32768 + r * 4096 + t * 16);
#pragma unroll
      for (int r = 0; r < 4; ++r)
        gload_lds16(src + 16384 + r * 4096 + t * 16, lds + 49152 + r * 4096 + t * 16);
    }
    // convert x regs -> subtiled bf16 XH (lds[0]) / XL (lds[16384])
    {
      unsigned uh[16], ul[16];
      const float* xf = (const float*)xv;
#pragma unroll
      for (int i = 0; i < 16; ++i) {
        const float v0 = xf[2 * i], v1 = xf[2 * i + 1];
        const unsigned short h0 = rneb(v0), h1 = rneb(v1);
        const unsigned short q0 = rneb(v0 - bf2f(h0)), q1 = rneb(v1 - bf2f(h1));
        uh[i] = (unsigned)h0 | ((unsigned)h1 << 16);
        ul[i] = (unsigned)q0 | ((unsigned)q1 << 16);
      }
      const int swap = (t >> 2) & 1;
#pragma unroll
      for (int c = 0; c < 2; ++c) {
        const int pb = pq * 2 + c;
        const int base = ((skk * 8 + pb) * 2 + sjh) * 512 + sg * 128 + skr * 32;
        uint4v Ah = {uh[c * 8 + 0], uh[c * 8 + 1], uh[c * 8 + 2], uh[c * 8 + 3]};
        uint4v Bh = {uh[c * 8 + 4], uh[c * 8 + 5], uh[c * 8 + 6], uh[c * 8 + 7]};
        uint4v Al = {ul[c * 8 + 0], ul[c * 8 + 1], ul[c * 8 + 2], ul[c * 8 + 3]};
        uint4v Bl = {ul[c * 8 + 4], ul[c * 8 + 5], ul[c * 8 + 6], ul[c * 8 + 7]};
        if (swap) {
          *(uint4v*)(lds + base + 16) = Bh; *(uint4v*)(lds + base) = Ah;
          *(uint4v*)(lds + 16384 + base + 16) = Bl; *(uint4v*)(lds + 16384 + base) = Al;
        } else {
          *(uint4v*)(lds + base) = Ah; *(uint4v*)(lds + base + 16) = Bh;
          *(uint4v*)(lds + 16384 + base) = Al; *(uint4v*)(lds + 16384 + base + 16) = Bl;
        }
      }
    }
    __syncthreads();
    if (s < 3) {  // prefetch next slice (overlaps MFMA below)
      const float* xr = x + (size_t)((s + 1) * 64 + sk) * HWc + p0 + pq * 32;
#pragma unroll
      for (int i = 0; i < 8; ++i) xv[i] = *(const float4*)(xr + i * 4);
    }
    // MFMA: passes (Wh,Xh),(Wh,Xl),(Wl,Xh), kk = 0..1 (K=32 each)
#pragma unroll
    for (int pass = 0; pass < 3; ++pass) {
      const unsigned Ab = 32768u + (pass == 2 ? 16384u : 0u);
      const unsigned Bbs = (pass == 1 ? 16384u : 0u);
#pragma unroll
      for (int kk = 0; kk < 2; ++kk) {
        short8 af[4];
#pragma unroll
        for (int m = 0; m < 4; ++m)
          af[m] = *(const short8*)(lds + Ab + (unsigned)((wr * 64 + m * 16 + ln) * 128) +
                                   (unsigned)((((kk * 4) + g) ^ l7) << 4));
        uint2v b0[4], b1[4];
#pragma unroll
        for (int n = 0; n < 4; ++n) {
          const unsigned a = ldsb + Bbs +
              (unsigned)(((kk * 8 + wc * 4 + n) * 2) * 512 + g * 128 + ln * 2);
          TRREAD(b0[n], a);
          TRREAD(b1[n], a + 512u);
        }
        asm volatile("s_waitcnt lgkmcnt(0)" ::: "memory");
        __builtin_amdgcn_sched_barrier(0);
#pragma unroll
        for (int n = 0; n < 4; ++n) {
          union { uint2v u2[2]; short8 s8; } uu;
          uu.u2[0] = b0[n]; uu.u2[1] = b1[n];
#pragma unroll
          for (int m = 0; m < 4; ++m)
            acc[m][n] = __builtin_amdgcn_mfma_f32_16x16x32_bf16(af[m], uu.s8, acc[m][n], 0, 0, 0);
        }
      }
    }
  }

  __syncthreads();
  // BN + mish + split -> FH (lds[0]) / FL (lds[32768]) as [p][cf] bf16, slot-swizzled
#pragma unroll
  for (int m = 0; m < 4; ++m)
#pragma unroll
    for (int n = 0; n < 4; ++n) {
      const int p = wc * 64 + n * 16 + ln;
      const int mskp = ((p & 7) << 1) | ((p >> 3) & 1);
      unsigned short hh[4], lo2[4];
#pragma unroll
      for (int r = 0; r < 4; ++r) {
        const float v = acc[m][n][r] * gval[m][r] + bval[m][r];
        const float e = expf(v);
        const float u = 1.f + e, u2 = u * u;
        const float mi = v * (u2 - 1.f) / (u2 + 1.f);
        const float fv = (v > 20.f) ? v : mi;
        hh[r] = rneb(fv);
        lo2[r] = rneb(fv - bf2f(hh[r]));
      }
      const int slot = wr * 8 + m * 2 + (g >> 1);
      const unsigned addr = (unsigned)(p * 256 + ((slot ^ mskp) << 4) + (g & 1) * 8);
      uint2v vh = {(unsigned)hh[0] | ((unsigned)hh[1] << 16), (unsigned)hh[2] | ((unsigned)hh[3] << 16)};
      uint2v vl = {(unsigned)lo2[0] | ((unsigned)lo2[1] << 16), (unsigned)lo2[2] | ((unsigned)lo2[3] << 16)};
      *(uint2v*)(lds + addr) = vh;
      *(uint2v*)(lds + 32768 + addr) = vl;
    }
  __syncthreads();

  // Phase 2: h = f @ mw1 ; passes (FH,MH),(FH,ML),(FL,MH)
  f32x4 acc2[4][4] = {};
#pragma unroll
  for (int pass = 0; pass < 3; ++pass) {
    const unsigned Ab = (pass == 2) ? 32768u : 0u;
    const char* Bm = mwt + (pass == 1 ? 32768 : 0);
#pragma unroll
    for (int kk = 0; kk < 4; ++kk) {
      short8 af[4], bfr[4];
#pragma unroll
      for (int m = 0; m < 4; ++m) {
        const int p = wr * 64 + m * 16 + ln;
        const int mskp = ((p & 7) << 1) | ((p >> 3) & 1);
        const int slot = kk * 4 + g;
        af[m] = *(const short8*)(lds + Ab + (unsigned)(p * 256 + ((slot ^ mskp) << 4)));
      }
#pragma unroll
      for (int n = 0; n < 4; ++n) {
        const int co = wc * 64 + n * 16 + ln;
        bfr[n] = *(const short8*)(Bm + (size_t)co * 256 + (kk * 32 + g * 8) * 2);
      }
#pragma unroll
      for (int m = 0; m < 4; ++m)
#pragma unroll
        for (int n = 0; n < 4; ++n)
          acc2[m][n] = __builtin_amdgcn_mfma_f32_16x16x32_bf16(af[m], bfr[n], acc2[m][n], 0, 0, 0);
    }
  }
  __syncthreads();

  // stage h f32 [p][co] (swizzled) then coalesced float4 store
#pragma unroll
  for (int m = 0; m < 4; ++m)
#pragma unroll
    for (int n = 0; n < 4; ++n)
#pragma unroll
      for (int r = 0; r < 4; ++r) {
        const int p = wr * 64 + m * 16 + g * 4 + r;
        const int co = wc * 64 + n * 16 + ln;
        const unsigned addr = (unsigned)(p * 512 + (((co >> 2) ^ (p & 7)) << 4) + (co & 3) * 4);
        *(float*)(lds + addr) = acc2[m][n][r];
      }
  __syncthreads();
  {
    float* H = ws + W_R0 + (size_t)mb * HWc * 128;
    const int p = t >> 1, half = t & 1;
    float* dst = H + (size_t)(p0 + p) * 128 + half * 64;
#pragma unroll
    for (int j = 0; j < 16; ++j) {
      const int cs = half * 16 + j;
      const f32x4 v = *(const f32x4*)(lds + (unsigned)(p * 512 + ((cs ^ (p & 7)) << 4)));
      *(f32x4*)(dst + j * 4) = v;
    }
  }
}

// ---------------- centc = gathered_feat @ pm + cvec ----------------
__global__ __launch_bounds__(256) void center_gemm(const float* __restrict__ f0,
                                                   const float* __restrict__ f1,
                                                   float* __restrict__ ws) {
  const int n0 = blockIdx.x * 128;
  const int t = threadIdx.x;
  __shared__ int rsrc[128];
  if (t < 128) {
    const int n = n0 + t;
    int r;
    if (n < BLc) r = n;
    else {
      const int m2 = n - BLc;
      const int b = m2 >> 12, lq = m2 & 4095;
      r = BLc + b * Ll + ((const int*)ws)[W_JINT + b * Ll + lq];
    }
    rsrc[t] = r;
  }
  __syncthreads();
  __shared__ float As[16][132];
  __shared__ float Wsm[16][128];
  const int ty = t >> 4, tx = t & 15;
  const int lr = t >> 2, lk = (t & 3) << 2;
  const int wcq = t >> 4, wd = (t & 15) << 3;
  const float* pm = ws + W_PM;
  float acc[8][8] = {};
  for (int k0 = 0; k0 < 256; k0 += 16) {
    const int r0 = rsrc[lr], r1 = rsrc[lr + 64];
    const float* pp0 = (r0 < BLc) ? (f0 + (size_t)r0 * 256) : (f1 + (size_t)(r0 - BLc) * 256);
    const float* pp1 = (r1 < BLc) ? (f0 + (size_t)r1 * 256) : (f1 + (size_t)(r1 - BLc) * 256);
    float4 a0 = *(const float4*)(pp0 + k0 + lk);
    float4 a1 = *(const float4*)(pp1 + k0 + lk);
    float4 w0 = *(const float4*)(pm + (size_t)(k0 + wcq) * 128 + wd);
    float4 w1 = *(const float4*)(pm + (size_t)(k0 + wcq) * 128 + wd + 4);
    __syncthreads();
    As[lk + 0][lr] = a0.x; As[lk + 1][lr] = a0.y; As[lk + 2][lr] = a0.z; As[lk + 3][lr] = a0.w;
    As[lk + 0][lr + 64] = a1.x; As[lk + 1][lr + 64] = a1.y; As[lk + 2][lr + 64] = a1.z; As[lk + 3][lr + 64] = a1.w;
    *(float4*)&Wsm[wcq][wd] = w0; *(float4*)&Wsm[wcq][wd + 4] = w1;
    __syncthreads();
#pragma unroll
    for (int k = 0; k < 16; ++k) {
      float a[8], b[8];
      *(float4*)&a[0] = *(const float4*)&As[k][ty * 8];
      *(float4*)&a[4] = *(const float4*)&As[k][ty * 8 + 4];
      *(float4*)&b[0] = *(const float4*)&Wsm[k][tx * 8];
      *(float4*)&b[4] = *(const float4*)&Wsm[k][tx * 8 + 4];
#pragma unroll
      for (int ii = 0; ii < 8; ++ii)
#pragma unroll
        for (int jj = 0; jj < 8; ++jj)
          acc[ii][jj] = fmaf(a[ii], b[jj], acc[ii][jj]);
    }
  }
  const float* cv = ws + W_CV;
#pragma unroll
  for (int ii = 0; ii < 8; ++ii)
#pragma unroll
    for (int jj = 0; jj < 8; ++jj)
      ws[W_CENT + (size_t)(n0 + ty * 8 + ii) * 128 + tx * 8 + jj] = acc[ii][jj] + cv[tx * 8 + jj];
}

// ---------------- local_desc = gather(h) + centc + pe ----------------
__global__ __launch_bounds__(256) void gather_out(const float* __restrict__ ws, float* __restrict__ out) {
  const int n = blockIdx.x;
  const int t = threadIdx.x;
  const int d = t & 127, th = t >> 7;
  int b, lq, mapsel;
  if (n < BLc) { mapsel = 0; b = n >> 12; lq = n & 4095; }
  else {
    mapsel = 1;
    const int m2 = n - BLc;
    b = m2 >> 12;
    lq = ((const int*)ws)[W_JINT + b * Ll + (m2 & 4095)];
  }
  const float* hb = ws + W_R0 + ((size_t)(mapsel * 2 + b) * HWc) * 128;
  const int y0 = ((lq >> 6) << 2) - 2, x0 = ((lq & 63) << 2) - 2;
  const float cvn = ws[W_CENT + (size_t)n * 128 + d];
  float* ob = out + (size_t)n * WWc * 128 + d;
  const float* pe = ws + W_PE;
  for (int m = th; m < WWc; m += 2) {
    const int dy = m / 5, dx = m - dy * 5;
    const int y = y0 + dy, x = x0 + dx;
    float hv = 0.f;
    if ((unsigned)y < 256u && (unsigned)x < 256u)
      hv = hb[((size_t)(y << 8) + x) * 128 + d];
    ob[(size_t)m * 128] = hv + cvn + pe[m * 128 + d];
  }
}

// ---------------- launcher ----------------
extern "C" void kernel_launch(void* const* d_in, const int* in_sizes, int n_in,
                              void* d_out, int out_size, void* d_ws, size_t ws_size,
                              hipStream_t stream) {
  (void)in_sizes; (void)n_in; (void)out_size; (void)ws_size;
  const float* f0  = (const float*)d_in[0];
  const float* f1  = (const float*)d_in[1];
  const float* fm0 = (const float*)d_in[2];
  const float* fm1 = (const float*)d_in[3];
  const float* cw  = (const float*)d_in[4];
  const float* cb  = (const float*)d_in[5];
  const float* bg  = (const float*)d_in[6];
  const float* bbt = (const float*)d_in[7];
  const float* bm  = (const float*)d_in[8];
  const float* bv  = (const float*)d_in[9];
  const float* pw  = (const float*)d_in[10];
  const float* pb  = (const float*)d_in[11];
  const float* mw  = (const float*)d_in[12];
  const float* mbb = (const float*)d_in[13];
  float* out = (float*)d_out;
  float* ws  = (float*)d_ws;

  prep_kernel<<<258, 128, 0, stream>>>(pw, pb, mw, mbb, ws);
  prep2_kernel<<<385, 128, 0, stream>>>(cw, mw, cb, bg, bbt, bm, bv, ws);
  sim_gemm<<<dim3(32, 32, 2), 256, 0, stream>>>(f0, f1, ws + W_R0);
  row_stats<<<BLc, 256, 0, stream>>>(ws + W_R0, ws);
  col_stats<<<dim3(32, 16), 256, 0, stream>>>(ws + W_R0, ws);
  col_merge<<<32, 256, 0, stream>>>(ws);
  cm_kernel<<<BLc, 256, 0, stream>>>(ws, out);
  colcm_stats<<<dim3(32, 16), 256, 0, stream>>>(out, ws);
  finalize_kernel<<<32, 256, 0, stream>>>(ws, out);
  // fused fine-feature path (writes h into W_R0 region after cm phase is done)
  fused_conv_kernel<<<dim3(512, 4), 256, 0, stream>>>(fm0, fm1, ws);
  center_gemm<<<128, 256, 0, stream>>>(f0, f1, ws);
  gather_out<<<NCRc, 256, 0, stream>>>(ws, out);
}